// Round 8
// baseline (1160.489 us; speedup 1.0000x reference)
//
#include <hip/hip_runtime.h>

#define OBS   32
#define NC    512
#define CD    16
#define HD    256
#define BATCH 8192
#define EPS   4e-3f

// ---------------------------------------------------------------------------
// Kernel 0: codebook squared norms (fp32 + fp64) and flag-counter zeroing.
// ---------------------------------------------------------------------------
__global__ void cb_norms_kernel(const float* __restrict__ cb,
                                float* __restrict__ n32, double* __restrict__ n64,
                                int* __restrict__ fcnt) {
    if (blockIdx.x == 0 && threadIdx.x == 0) *fcnt = 0;
    int c = blockIdx.x * blockDim.x + threadIdx.x;
    if (c >= NC) return;
    const float* r = cb + c * CD;
    float s32 = 0.f; double s64 = 0.0;
    #pragma unroll
    for (int j = 0; j < CD; ++j) {
        float v = r[j];
        s32 = fmaf(v, v, s32);
        s64 = fma((double)v, (double)v, s64);
    }
    n32[c] = s32; n64[c] = s64;
}

// ---------------------------------------------------------------------------
// Kernel 1: fp32 fused encoder + quantize prefilter. One block = one batch
// row (32 tokens), 128 threads, per-thread tile 8 tok x 8 cols. Columns are
// split {4s..4s+3} u {128+4s..128+4s+3} so every ds_read_b128 spans all 8
// bank-quads (full-BW). __launch_bounds__(128,1) lifts the VGPR cap (R7's
// (128,2) caused scratch spills: 93 MB WRITE_SIZE). W1 staged in 16-row LDS
// chunks with register prefetch. fp32 top-2 gap < EPS -> fp64 fixup kernel.
// ---------------------------------------------------------------------------
__global__ void __launch_bounds__(128, 1) encoder_kernel(
    const float* __restrict__ obs,
    const float* __restrict__ W0, const float* __restrict__ B0,
    const float* __restrict__ W1, const float* __restrict__ B1,
    const float* __restrict__ W2, const float* __restrict__ B2,
    const float* __restrict__ cb, const float* __restrict__ n32,
    int* __restrict__ idxbuf, int* __restrict__ fcnt, int* __restrict__ flist)
{
    // smem: hbuf[32][260] (8320 f) + wchunk[16][260] (4160 f) = 12480 floats.
    // Phase D overlays smem as cbs[512][18] (9216 f; slot16 = |c|^2).
    __shared__ float smem[12480];       // 49920 B
    __shared__ float embs[OBS * CD];    //  2048 B
    __shared__ float xrow[OBS];         //   128 B  (52096 B -> 3 blk/CU)
    float* const hbuf   = smem;
    float* const wchunk = smem + 8320;

    const int tid = threadIdx.x;
    const int blk = blockIdx.x;

    if (tid < OBS) xrow[tid] = obs[blk * OBS + tid];

    // W1 staging slice: row pr, 128B run at col pc (32 floats / thread)
    const int pr = tid & 15;
    const int pc = (tid >> 4) * 32;
    float4 pf[8];
    {   // prefetch chunk 0 (lands during phase A)
        const float4* p = (const float4*)(W1 + pr * HD + pc);
        #pragma unroll
        for (int i = 0; i < 8; ++i) pf[i] = p[i];
    }
    __syncthreads();                    // xrow visible

    // ---- phase A: h0[t][j] = relu(x_t*W0[0,j] + W0[1+t,j] + b0[j]) ----
    {
        const int ja = tid, jb = tid + 128;
        const float w0a = W0[ja], w0b = W0[jb];
        const float b0a = B0[ja], b0b = B0[jb];
        for (int t = 0; t < OBS; ++t) {
            float xa = xrow[t];
            float pa = fmaf(xa, w0a, W0[(1 + t) * HD + ja]) + b0a;
            float pb = fmaf(xa, w0b, W0[(1 + t) * HD + jb]) + b0b;
            hbuf[t * 260 + ja] = fmaxf(pa, 0.f);
            hbuf[t * 260 + jb] = fmaxf(pb, 0.f);
        }
    }

    // ---- phase B: h1 = relu(h0 @ W1 + b1); 8 tokens x 8 cols / thread ----
    const int c0a = (tid & 31) * 4;     // cols {c0a..+3}
    const int c0b = c0a + 128;          // and  {c0b..+3}: all 8 quads covered
    const int t0  = (tid >> 5) * 8;     // 4 token groups (2/wave: broadcast)

    float acc[8][8];
    #pragma unroll
    for (int tt = 0; tt < 8; ++tt)
        #pragma unroll
        for (int u = 0; u < 8; ++u) acc[tt][u] = 0.f;

    for (int kc = 0; kc < 16; ++kc) {
        __syncthreads();                // prev chunk reads done (kc=0: phase A)
        {
            float4* dst = (float4*)&wchunk[pr * 260 + pc];
            #pragma unroll
            for (int i = 0; i < 8; ++i) dst[i] = pf[i];
        }
        __syncthreads();                // chunk visible
        if (kc < 15) {                  // prefetch next chunk during FMA
            const float4* p = (const float4*)(W1 + ((kc + 1) * 16 + pr) * HD + pc);
            #pragma unroll
            for (int i = 0; i < 8; ++i) pf[i] = p[i];
        }
        const int kb = kc * 16;
        #pragma unroll
        for (int kk = 0; kk < 16; kk += 4) {
            float4 hv[8];
            #pragma unroll
            for (int tt = 0; tt < 8; ++tt)
                hv[tt] = *(const float4*)&hbuf[(t0 + tt) * 260 + kb + kk];
            #pragma unroll
            for (int q = 0; q < 4; ++q) {
                float4 wa = *(const float4*)&wchunk[(kk + q) * 260 + c0a];
                float4 wb = *(const float4*)&wchunk[(kk + q) * 260 + c0b];
                #pragma unroll
                for (int tt = 0; tt < 8; ++tt) {
                    float h = (q == 0) ? hv[tt].x : (q == 1) ? hv[tt].y
                             : (q == 2) ? hv[tt].z : hv[tt].w;
                    acc[tt][0] = fmaf(h, wa.x, acc[tt][0]);
                    acc[tt][1] = fmaf(h, wa.y, acc[tt][1]);
                    acc[tt][2] = fmaf(h, wa.z, acc[tt][2]);
                    acc[tt][3] = fmaf(h, wa.w, acc[tt][3]);
                    acc[tt][4] = fmaf(h, wb.x, acc[tt][4]);
                    acc[tt][5] = fmaf(h, wb.y, acc[tt][5]);
                    acc[tt][6] = fmaf(h, wb.z, acc[tt][6]);
                    acc[tt][7] = fmaf(h, wb.w, acc[tt][7]);
                }
            }
        }
    }

    {   // h1 = relu(acc + b1) -> hbuf
        float4 b1a = *(const float4*)(B1 + c0a);
        float4 b1b = *(const float4*)(B1 + c0b);
        #pragma unroll
        for (int tt = 0; tt < 8; ++tt) {
            float4 oa, ob;
            oa.x = fmaxf(acc[tt][0] + b1a.x, 0.f);
            oa.y = fmaxf(acc[tt][1] + b1a.y, 0.f);
            oa.z = fmaxf(acc[tt][2] + b1a.z, 0.f);
            oa.w = fmaxf(acc[tt][3] + b1a.w, 0.f);
            ob.x = fmaxf(acc[tt][4] + b1b.x, 0.f);
            ob.y = fmaxf(acc[tt][5] + b1b.y, 0.f);
            ob.z = fmaxf(acc[tt][6] + b1b.z, 0.f);
            ob.w = fmaxf(acc[tt][7] + b1b.w, 0.f);
            *(float4*)&hbuf[(t0 + tt) * 260 + c0a] = oa;
            *(float4*)&hbuf[(t0 + tt) * 260 + c0b] = ob;
        }
    }
    __syncthreads();                    // h1 visible; wchunk reads done

    {   // stage W2^T into wchunk: W2t[d][k], stride 260
        const int d = tid & 15, k0 = (tid >> 4) * 32;
        float tmp[32];
        #pragma unroll
        for (int i = 0; i < 32; ++i) tmp[i] = W2[(k0 + i) * CD + d];
        float4* dst = (float4*)&wchunk[d * 260 + k0];
        #pragma unroll
        for (int i = 0; i < 8; ++i)
            dst[i] = make_float4(tmp[4*i], tmp[4*i+1], tmp[4*i+2], tmp[4*i+3]);
    }
    __syncthreads();

    // ---- phase C: emb = h1 @ W2 + b2; thread = (token, 4 dims) ----
    {
        const int t   = tid >> 2;
        const int dp0 = (tid & 3) * 4;
        float a0 = 0.f, a1 = 0.f, a2 = 0.f, a3 = 0.f;
        #pragma unroll 4
        for (int k = 0; k < HD; k += 4) {
            float4 h  = *(const float4*)&hbuf[t * 260 + k];
            float4 w0_ = *(const float4*)&wchunk[(dp0 + 0) * 260 + k];
            float4 w1_ = *(const float4*)&wchunk[(dp0 + 1) * 260 + k];
            float4 w2_ = *(const float4*)&wchunk[(dp0 + 2) * 260 + k];
            float4 w3_ = *(const float4*)&wchunk[(dp0 + 3) * 260 + k];
            a0 = fmaf(h.x, w0_.x, a0); a0 = fmaf(h.y, w0_.y, a0);
            a0 = fmaf(h.z, w0_.z, a0); a0 = fmaf(h.w, w0_.w, a0);
            a1 = fmaf(h.x, w1_.x, a1); a1 = fmaf(h.y, w1_.y, a1);
            a1 = fmaf(h.z, w1_.z, a1); a1 = fmaf(h.w, w1_.w, a1);
            a2 = fmaf(h.x, w2_.x, a2); a2 = fmaf(h.y, w2_.y, a2);
            a2 = fmaf(h.z, w2_.z, a2); a2 = fmaf(h.w, w2_.w, a2);
            a3 = fmaf(h.x, w3_.x, a3); a3 = fmaf(h.y, w3_.y, a3);
            a3 = fmaf(h.z, w3_.z, a3); a3 = fmaf(h.w, w3_.w, a3);
        }
        float4 bb = *(const float4*)(B2 + dp0);
        *(float4*)&embs[t * CD + dp0] =
            make_float4(a0 + bb.x, a1 + bb.y, a2 + bb.z, a3 + bb.w);
    }
    __syncthreads();                    // embs done; hbuf/wchunk reads done

    // stage codebook + norm into overlay, stride 18 (2-way max: free)
    for (int r = tid; r < NC; r += 128) {
        const float2* src = (const float2*)(cb + r * CD);
        float* dst = &smem[r * 18];
        #pragma unroll
        for (int i = 0; i < 8; ++i) *(float2*)&dst[2 * i] = src[i];
        dst[16] = n32[r];
    }
    __syncthreads();

    // ---- phase D: exact fp32 top-2 over 512 codes; flag near-ties ----
    {
        const int s  = tid & 15;        // 16 lanes/token-group, 32 codes each
        const int tD = (tid >> 4) * 4;  // 8 groups x 4 tokens = 32
        float e[4][CD];
        #pragma unroll
        for (int j = 0; j < 4; ++j)
            #pragma unroll
            for (int q4 = 0; q4 < 4; ++q4) {
                float4 v = *(const float4*)&embs[(tD + j) * CD + q4 * 4];
                e[j][q4 * 4 + 0] = v.x; e[j][q4 * 4 + 1] = v.y;
                e[j][q4 * 4 + 2] = v.z; e[j][q4 * 4 + 3] = v.w;
            }
        float d1[4], d2[4]; int i1[4], i2[4];
        #pragma unroll
        for (int j = 0; j < 4; ++j) { d1[j] = d2[j] = 3.4e38f; i1[j] = i2[j] = 0x7fffffff; }

        for (int cc = 0; cc < 32; ++cc) {
            const int ci = cc * 16 + s;
            const float* cr = &smem[ci * 18];
            float c_[CD];
            #pragma unroll
            for (int i = 0; i < 8; ++i) {
                float2 p = *(const float2*)&cr[2 * i];
                c_[2 * i] = p.x; c_[2 * i + 1] = p.y;
            }
            float cn = cr[16];
            #pragma unroll
            for (int j = 0; j < 4; ++j) {
                float dA = 0.f, dB = 0.f;
                #pragma unroll
                for (int q = 0; q < 8; ++q) {
                    dA = fmaf(c_[2 * q],     e[j][2 * q],     dA);
                    dB = fmaf(c_[2 * q + 1], e[j][2 * q + 1], dB);
                }
                float d = fmaf(-2.f, dA + dB, cn);
                if (d < d1[j])      { d2[j] = d1[j]; i2[j] = i1[j]; d1[j] = d; i1[j] = ci; }
                else if (d < d2[j]) { d2[j] = d;  i2[j] = ci; }
            }
        }
        // width-16 top-2 merge reduce (tie -> low index)
        #pragma unroll
        for (int off = 8; off >= 1; off >>= 1) {
            #pragma unroll
            for (int j = 0; j < 4; ++j) {
                float od1 = __shfl_down(d1[j], off, 16);
                int   oi1 = __shfl_down(i1[j], off, 16);
                float od2 = __shfl_down(d2[j], off, 16);
                int   oi2 = __shfl_down(i2[j], off, 16);
                bool ob = (od1 < d1[j]) || (od1 == d1[j] && oi1 < i1[j]);
                float n1d, n2d; int n1i, n2i;
                if (ob) {
                    n1d = od1; n1i = oi1;
                    bool t2 = (d1[j] < od2) || (d1[j] == od2 && i1[j] < oi2);
                    n2d = t2 ? d1[j] : od2; n2i = t2 ? i1[j] : oi2;
                } else {
                    n1d = d1[j]; n1i = i1[j];
                    bool t2 = (od1 < d2[j]) || (od1 == d2[j] && oi1 < i2[j]);
                    n2d = t2 ? od1 : d2[j]; n2i = t2 ? oi1 : i2[j];
                }
                d1[j] = n1d; i1[j] = n1i; d2[j] = n2d; i2[j] = n2i;
            }
        }
        if (s == 0) {
            int nf = 0, ft[4];
            #pragma unroll
            for (int j = 0; j < 4; ++j) {
                int T = blk * OBS + tD + j;
                idxbuf[T] = i1[j];
                if (d2[j] - d1[j] < EPS) ft[nf++] = T;
            }
            if (nf) {
                int base = atomicAdd(fcnt, nf);
                for (int k = 0; k < nf; ++k) flist[base + k] = ft[k];
            }
        }
    }
}

// ---------------------------------------------------------------------------
// Kernel 2: fp64 exact re-solve for flagged (near-tie) tokens. One block per
// flagged token, grid-stride. Overwrites idxbuf[T] with the fp64 argmin.
// ---------------------------------------------------------------------------
__global__ void __launch_bounds__(256) fixup_kernel(
    const float* __restrict__ obs,
    const float* __restrict__ W0, const float* __restrict__ B0,
    const float* __restrict__ W1, const float* __restrict__ B1,
    const float* __restrict__ W2, const float* __restrict__ B2,
    const float* __restrict__ cb, const double* __restrict__ n64,
    const int* __restrict__ fcnt, const int* __restrict__ flist,
    int* __restrict__ idxbuf)
{
    __shared__ double h0s[HD];
    __shared__ double h1s[HD];
    __shared__ double ep[16][17];
    __shared__ double es[CD];
    __shared__ double dmin[256];
    __shared__ int    imin[256];

    int n = *fcnt;
    if (n > BATCH * OBS) n = BATCH * OBS;
    const int j = threadIdx.x;

    for (int f = blockIdx.x; f < n; f += gridDim.x) {
        const int T = flist[f];
        const int b = T >> 5, t = T & 31;
        const double x = (double)obs[b * OBS + t];
        {
            double a = fma(x, (double)W0[j], (double)W0[(1 + t) * HD + j])
                     + (double)B0[j];
            h0s[j] = a > 0.0 ? a : 0.0;
        }
        __syncthreads();
        {
            double s = 0.0;
            for (int k = 0; k < HD; ++k)
                s = fma(h0s[k], (double)W1[k * HD + j], s);
            s += (double)B1[j];
            h1s[j] = s > 0.0 ? s : 0.0;
        }
        __syncthreads();
        {
            const int d = j & 15, part = j >> 4;
            double s = 0.0;
            for (int k = part * 16; k < part * 16 + 16; ++k)
                s = fma(h1s[k], (double)W2[k * CD + d], s);
            ep[part][d] = s;
        }
        __syncthreads();
        if (j < CD) {
            double s = 0.0;
            for (int p = 0; p < 16; ++p) s += ep[p][j];
            es[j] = s + (double)B2[j];
        }
        __syncthreads();
        {
            double best = 1e300; int bi = 0x7fffffff;
            for (int c = j; c < NC; c += 256) {
                double dot = 0.0;
                #pragma unroll
                for (int q = 0; q < CD; ++q)
                    dot = fma(es[q], (double)cb[c * CD + q], dot);
                double D = n64[c] - 2.0 * dot;
                if (D < best || (D == best && c < bi)) { best = D; bi = c; }
            }
            dmin[j] = best; imin[j] = bi;
        }
        __syncthreads();
        if (j == 0) {
            double best = dmin[0]; int bi = imin[0];
            for (int k = 1; k < 256; ++k)
                if (dmin[k] < best || (dmin[k] == best && imin[k] < bi)) {
                    best = dmin[k]; bi = imin[k];
                }
            idxbuf[T] = bi;
        }
        __syncthreads();
    }
}

// ---------------------------------------------------------------------------
// Kernel 3: decoder MLP 512 -> 256 -> 256 -> 32, 16 batch rows per block.
// Gathers q rows from the codebook via idxbuf (q never materialized).
// ---------------------------------------------------------------------------
__global__ void __launch_bounds__(256) decoder_kernel(
    const int* __restrict__ idx, const float* __restrict__ cbk,
    const float* __restrict__ W0, const float* __restrict__ B0,
    const float* __restrict__ W1, const float* __restrict__ B1,
    const float* __restrict__ W2, const float* __restrict__ B2,
    float* __restrict__ out)
{
    __shared__ float qb[16][512];   // 32 KB: q, later reused as h2[16][256]
    __shared__ float hb[16][256];   // 16 KB
    const int tid = threadIdx.x;
    const int row0 = blockIdx.x * 16;

    {   // gather q rows: 2 tokens per thread from L1-resident codebook
        const int base = row0 * OBS;
        #pragma unroll
        for (int m = 0; m < 2; ++m) {
            int g = tid * 2 + m;
            int ciq = idx[base + g];
            const float4* src = (const float4*)(cbk + ciq * CD);
            float4* dst = (float4*)&qb[g >> 5][(g & 31) * CD];
            dst[0] = src[0]; dst[1] = src[1]; dst[2] = src[2]; dst[3] = src[3];
        }
    }
    __syncthreads();

    const int jg = tid & 63, tg = tid >> 6;
    const int j0 = jg * 4, r0 = tg * 4;

    // ---- layer 0: K=512 ----
    {
        float acA[4][4], acB[4][4];
        #pragma unroll
        for (int tt = 0; tt < 4; ++tt)
            #pragma unroll
            for (int u = 0; u < 4; ++u) { acA[tt][u] = 0.f; acB[tt][u] = 0.f; }
        for (int k = 0; k < 512; k += 4) {
            float hr[4][4];
            #pragma unroll
            for (int tt = 0; tt < 4; ++tt) {
                float4 hv = *(const float4*)&qb[r0 + tt][k];
                hr[tt][0] = hv.x; hr[tt][1] = hv.y; hr[tt][2] = hv.z; hr[tt][3] = hv.w;
            }
            #pragma unroll
            for (int p = 0; p < 4; ++p) {
                float4 w = *(const float4*)(W0 + (k + p) * 256 + j0);
                if (p < 2) {
                    #pragma unroll
                    for (int tt = 0; tt < 4; ++tt) {
                        acA[tt][0] = fmaf(hr[tt][p], w.x, acA[tt][0]);
                        acA[tt][1] = fmaf(hr[tt][p], w.y, acA[tt][1]);
                        acA[tt][2] = fmaf(hr[tt][p], w.z, acA[tt][2]);
                        acA[tt][3] = fmaf(hr[tt][p], w.w, acA[tt][3]);
                    }
                } else {
                    #pragma unroll
                    for (int tt = 0; tt < 4; ++tt) {
                        acB[tt][0] = fmaf(hr[tt][p], w.x, acB[tt][0]);
                        acB[tt][1] = fmaf(hr[tt][p], w.y, acB[tt][1]);
                        acB[tt][2] = fmaf(hr[tt][p], w.z, acB[tt][2]);
                        acB[tt][3] = fmaf(hr[tt][p], w.w, acB[tt][3]);
                    }
                }
            }
        }
        #pragma unroll
        for (int tt = 0; tt < 4; ++tt)
            #pragma unroll
            for (int u = 0; u < 4; ++u)
                hb[r0 + tt][j0 + u] = fmaxf((acA[tt][u] + acB[tt][u]) + B0[j0 + u], 0.f);
    }
    __syncthreads();

    // ---- layer 1: K=256, write h2 into qb storage ----
    float* h2 = &qb[0][0];
    {
        float acA[4][4], acB[4][4];
        #pragma unroll
        for (int tt = 0; tt < 4; ++tt)
            #pragma unroll
            for (int u = 0; u < 4; ++u) { acA[tt][u] = 0.f; acB[tt][u] = 0.f; }
        for (int k = 0; k < 256; k += 4) {
            float hr[4][4];
            #pragma unroll
            for (int tt = 0; tt < 4; ++tt) {
                float4 hv = *(const float4*)&hb[r0 + tt][k];
                hr[tt][0] = hv.x; hr[tt][1] = hv.y; hr[tt][2] = hv.z; hr[tt][3] = hv.w;
            }
            #pragma unroll
            for (int p = 0; p < 4; ++p) {
                float4 w = *(const float4*)(W1 + (k + p) * 256 + j0);
                if (p < 2) {
                    #pragma unroll
                    for (int tt = 0; tt < 4; ++tt) {
                        acA[tt][0] = fmaf(hr[tt][p], w.x, acA[tt][0]);
                        acA[tt][1] = fmaf(hr[tt][p], w.y, acA[tt][1]);
                        acA[tt][2] = fmaf(hr[tt][p], w.z, acA[tt][2]);
                        acA[tt][3] = fmaf(hr[tt][p], w.w, acA[tt][3]);
                    }
                } else {
                    #pragma unroll
                    for (int tt = 0; tt < 4; ++tt) {
                        acB[tt][0] = fmaf(hr[tt][p], w.x, acB[tt][0]);
                        acB[tt][1] = fmaf(hr[tt][p], w.y, acB[tt][1]);
                        acB[tt][2] = fmaf(hr[tt][p], w.z, acB[tt][2]);
                        acB[tt][3] = fmaf(hr[tt][p], w.w, acB[tt][3]);
                    }
                }
            }
        }
        __syncthreads();
        #pragma unroll
        for (int tt = 0; tt < 4; ++tt)
            #pragma unroll
            for (int u = 0; u < 4; ++u)
                h2[(r0 + tt) * 256 + j0 + u] =
                    fmaxf((acA[tt][u] + acB[tt][u]) + B1[j0 + u], 0.f);
    }
    __syncthreads();

    // ---- layer 2: N=32 output, no relu ----
    {
        const int c  = tid & 31;
        const int rg = tid >> 5;
        for (int rr = rg; rr < 16; rr += 8) {
            float a0 = 0.f, a1 = 0.f, a2 = 0.f, a3 = 0.f;
            #pragma unroll 4
            for (int k = 0; k < 256; k += 4) {
                float4 hv = *(const float4*)&h2[rr * 256 + k];
                a0 = fmaf(hv.x, W2[(k + 0) * 32 + c], a0);
                a1 = fmaf(hv.y, W2[(k + 1) * 32 + c], a1);
                a2 = fmaf(hv.z, W2[(k + 2) * 32 + c], a2);
                a3 = fmaf(hv.w, W2[(k + 3) * 32 + c], a3);
            }
            out[(row0 + rr) * 32 + c] = ((a0 + a1) + (a2 + a3)) + B2[c];
        }
    }
}

// ---------------------------------------------------------------------------
extern "C" void kernel_launch(void* const* d_in, const int* in_sizes, int n_in,
                              void* d_out, int out_size, void* d_ws, size_t ws_size,
                              hipStream_t stream) {
    (void)in_sizes; (void)n_in; (void)out_size; (void)ws_size;
    const float* obs = (const float*)d_in[0];
    const float* eW0 = (const float*)d_in[1];
    const float* eb0 = (const float*)d_in[2];
    const float* eW1 = (const float*)d_in[3];
    const float* eb1 = (const float*)d_in[4];
    const float* eW2 = (const float*)d_in[5];
    const float* eb2 = (const float*)d_in[6];
    const float* dW0 = (const float*)d_in[7];
    const float* db0 = (const float*)d_in[8];
    const float* dW1 = (const float*)d_in[9];
    const float* db1 = (const float*)d_in[10];
    const float* dW2 = (const float*)d_in[11];
    const float* db2 = (const float*)d_in[12];
    const float* cb  = (const float*)d_in[13];

    char*   ws    = (char*)d_ws;
    float*  n32   = (float*)ws;                          // 2 KB
    double* n64   = (double*)(ws + 4096);                // 4 KB
    int*    fcnt  = (int*)(ws + 8192);                   // 4 B
    int*    flist = (int*)(ws + 8448);                   // 1 MB (worst case)
    int*    idxb  = (int*)(ws + 8448 + 1048576);         // 1 MB

    cb_norms_kernel<<<2, 256, 0, stream>>>(cb, n32, n64, fcnt);
    encoder_kernel<<<BATCH, 128, 0, stream>>>(obs, eW0, eb0, eW1, eb1, eW2, eb2,
                                              cb, n32, idxb, fcnt, flist);
    fixup_kernel<<<256, 256, 0, stream>>>(obs, eW0, eb0, eW1, eb1, eW2, eb2,
                                          cb, n64, fcnt, flist, idxb);
    decoder_kernel<<<BATCH / 16, 256, 0, stream>>>(idxb, cb, dW0, db0, dW1, db1,
                                                   dW2, db2, (float*)d_out);
}

// Round 9
// 595.707 us; speedup vs baseline: 1.9481x; 1.9481x over previous
//
#include <hip/hip_runtime.h>

#define OBS   32
#define NC    512
#define CD    16
#define HD    256
#define BATCH 8192
#define EPS   4e-3f

typedef unsigned short u16;
typedef unsigned int   u32;
typedef __attribute__((ext_vector_type(8))) short bf16x8;   // 8 bf16 = 4 VGPR
typedef __attribute__((ext_vector_type(4))) float f32x4;

__device__ __forceinline__ short f2bf(float x) {            // fp32 -> bf16 RNE
    union { float f; u32 u; } v; v.f = x;
    u32 r = (v.u + 0x7fffu + ((v.u >> 16) & 1u)) >> 16;
    return (short)r;
}
__device__ __forceinline__ float bf2f(short s) {
    union { u32 u; float f; } v; v.u = ((u32)(u16)s) << 16; return v.f;
}

// ---------------------------------------------------------------------------
// Kernel 0 (prep): codebook norms + fcnt; W1 split into bf16 hi/lo in
// B-fragment order (chunk s = k>>5: [n][k&31], hi then lo, 32KB/chunk);
// W2 split into W2t[n][k] hi/lo (row stride 264).
// ---------------------------------------------------------------------------
__global__ void prep_kernel(const float* __restrict__ cb,
                            const float* __restrict__ W1,
                            const float* __restrict__ W2,
                            float* __restrict__ n32, double* __restrict__ n64,
                            int* __restrict__ fcnt,
                            u16* __restrict__ wsW1, u16* __restrict__ wsW2) {
    const int b = blockIdx.x, t = threadIdx.x;
    if (b == 0) {
        if (t == 0) *fcnt = 0;
        #pragma unroll
        for (int h = 0; h < 2; ++h) {
            int c = t + h * 256;
            const float* r = cb + c * CD;
            float s32 = 0.f; double s64 = 0.0;
            #pragma unroll
            for (int j = 0; j < CD; ++j) {
                float v = r[j];
                s32 = fmaf(v, v, s32);
                s64 = fma((double)v, (double)v, s64);
            }
            n32[c] = s32; n64[c] = s64;
        }
    } else if (b <= 256) {
        int e = (b - 1) * 256 + t;          // e = k*256 + n
        int k = e >> 8, n = e & 255;
        float w = W1[k * 256 + n];
        short hi = f2bf(w);
        short lo = f2bf(w - bf2f(hi));
        int s = k >> 5, koff = k & 31;
        wsW1[s * 16384 + n * 32 + koff]        = (u16)hi;
        wsW1[s * 16384 + 8192 + n * 32 + koff] = (u16)lo;
    } else {                                 // b == 257: W2 (4096 elems)
        #pragma unroll
        for (int i = 0; i < 16; ++i) {
            int e = t * 16 + i;              // e = k*16 + n
            int k = e >> 4, n = e & 15;
            float w = W2[k * CD + n];
            short hi = f2bf(w);
            short lo = f2bf(w - bf2f(hi));
            wsW2[n * 264 + k]        = (u16)hi;
            wsW2[4224 + n * 264 + k] = (u16)lo;
        }
    }
}

// ---------------------------------------------------------------------------
// Kernel 1: MFMA encoder. One block = one batch row (32 tokens), 256 thr.
// Wave w: M-tile mt=w&1 (16 tokens), N-half ng=w>>1 (8 N-tiles of 16).
// h0 lives in registers as A-fragments (split bf16 hi/lo); W1 B-frags read
// direct from the chunk-ordered global image; 3-MFMA split chain per tile.
// h1 packed (hi<<16|lo) into LDS, phase C (2 waves) MFMAs vs W2t, phase D
// fp32 top-2 + EPS flag -> fp64 fixup.
// ---------------------------------------------------------------------------
__global__ void __launch_bounds__(256) encoder_kernel(
    const float* __restrict__ obs,
    const float* __restrict__ W0, const float* __restrict__ B0,
    const float* __restrict__ B1, const float* __restrict__ B2,
    const u16* __restrict__ wsW1, const u16* __restrict__ wsW2,
    const float* __restrict__ cb, const float* __restrict__ n32,
    int* __restrict__ idxbuf, int* __restrict__ fcnt, int* __restrict__ flist)
{
    __shared__ u32   sbuf[9216];     // 36864 B: hpk[32][260] ∪ cbs[512][18]f
    __shared__ float embs[OBS * CD]; //  2048 B

    const int tid = threadIdx.x;
    const int blk = blockIdx.x;
    const int l   = tid & 63;
    const int wv  = tid >> 6;
    const int q   = l >> 4;          // quad 0..3
    const int ln  = l & 15;
    const int mt  = wv & 1;
    const int ng  = wv >> 1;

    // ---- phase A: h0 A-frags in registers (lane: m = mt*16+ln, k-slices) ----
    bf16x8 Ah[8], Al[8];
    {
        const int m = mt * 16 + ln;
        const float x = obs[blk * OBS + m];
        const float* W0r = W0 + (1 + m) * HD;
        #pragma unroll
        for (int s = 0; s < 8; ++s) {
            const int k0 = s * 32 + q * 8;
            float w0v[8], wmv[8], b0v[8];
            *(float4*)&w0v[0] = *(const float4*)(W0 + k0);
            *(float4*)&w0v[4] = *(const float4*)(W0 + k0 + 4);
            *(float4*)&wmv[0] = *(const float4*)(W0r + k0);
            *(float4*)&wmv[4] = *(const float4*)(W0r + k0 + 4);
            *(float4*)&b0v[0] = *(const float4*)(B0 + k0);
            *(float4*)&b0v[4] = *(const float4*)(B0 + k0 + 4);
            #pragma unroll
            for (int j = 0; j < 8; ++j) {
                float h = fmaxf(fmaf(x, w0v[j], wmv[j]) + b0v[j], 0.f);
                short hi = f2bf(h);
                short lo = f2bf(h - bf2f(hi));
                Ah[s][j] = hi; Al[s][j] = lo;
            }
        }
    }

    // ---- phase B: h1 = relu(h0 @ W1 + b1) via 3-pass split MFMA ----
    f32x4 acc[8];
    #pragma unroll
    for (int nt = 0; nt < 8; ++nt) acc[nt] = (f32x4){0.f, 0.f, 0.f, 0.f};

    {
        const u16* pB = wsW1 + (ng * 128 + ln) * 32 + q * 8;
        #pragma unroll
        for (int s = 0; s < 8; ++s) {
            const u16* ph = pB + s * 16384;
            const u16* pl = ph + 8192;
            #pragma unroll
            for (int nt = 0; nt < 8; ++nt) {
                bf16x8 Bh = *(const bf16x8*)(ph + nt * 512);
                bf16x8 Bl = *(const bf16x8*)(pl + nt * 512);
                f32x4 a = acc[nt];
                a = __builtin_amdgcn_mfma_f32_16x16x32_bf16(Ah[s], Bh, a, 0, 0, 0);
                a = __builtin_amdgcn_mfma_f32_16x16x32_bf16(Ah[s], Bl, a, 0, 0, 0);
                a = __builtin_amdgcn_mfma_f32_16x16x32_bf16(Al[s], Bh, a, 0, 0, 0);
                acc[nt] = a;
            }
        }
    }

    {   // h1 epilogue: relu(+b1), split, pack -> hpk[m][n] (stride 260)
        u32* hpk = sbuf;
        #pragma unroll
        for (int nt = 0; nt < 8; ++nt) {
            const int n = ng * 128 + nt * 16 + ln;
            const float b1 = B1[n];
            #pragma unroll
            for (int r = 0; r < 4; ++r) {
                float h = fmaxf(acc[nt][r] + b1, 0.f);
                short hi = f2bf(h);
                short lo = f2bf(h - bf2f(hi));
                const int mr = mt * 16 + q * 4 + r;
                hpk[mr * 260 + n] = ((u32)(u16)hi << 16) | (u32)(u16)lo;
            }
        }
    }
    __syncthreads();

    // ---- phase C: emb = h1 @ W2 + b2 (waves 0,1; M-tile = wv) ----
    if (wv < 2) {
        f32x4 ac = (f32x4){0.f, 0.f, 0.f, 0.f};
        const u32* pA  = sbuf + (wv * 16 + ln) * 260;
        const u16* pWh = wsW2 + ln * 264 + q * 8;
        const u16* pWl = pWh + 4224;
        #pragma unroll
        for (int s = 0; s < 8; ++s) {
            uint4 pa = *(const uint4*)(pA + s * 32 + q * 8);
            uint4 pb = *(const uint4*)(pA + s * 32 + q * 8 + 4);
            bf16x8 Ah2 = { (short)(pa.x >> 16), (short)(pa.y >> 16),
                           (short)(pa.z >> 16), (short)(pa.w >> 16),
                           (short)(pb.x >> 16), (short)(pb.y >> 16),
                           (short)(pb.z >> 16), (short)(pb.w >> 16) };
            bf16x8 Al2 = { (short)pa.x, (short)pa.y, (short)pa.z, (short)pa.w,
                           (short)pb.x, (short)pb.y, (short)pb.z, (short)pb.w };
            bf16x8 Bh = *(const bf16x8*)(pWh + s * 32);
            bf16x8 Bl = *(const bf16x8*)(pWl + s * 32);
            ac = __builtin_amdgcn_mfma_f32_16x16x32_bf16(Ah2, Bh, ac, 0, 0, 0);
            ac = __builtin_amdgcn_mfma_f32_16x16x32_bf16(Ah2, Bl, ac, 0, 0, 0);
            ac = __builtin_amdgcn_mfma_f32_16x16x32_bf16(Al2, Bh, ac, 0, 0, 0);
        }
        const float b2 = B2[ln];
        #pragma unroll
        for (int r = 0; r < 4; ++r)
            embs[(wv * 16 + q * 4 + r) * CD + ln] = ac[r] + b2;
    }
    __syncthreads();                 // embs ready; hpk dead

    // stage codebook + norm, stride 18 floats (2-way max: free)
    {
        float* cbf = (float*)sbuf;
        for (int r = tid; r < NC; r += 256) {
            const float2* src = (const float2*)(cb + r * CD);
            float* dst = cbf + r * 18;
            #pragma unroll
            for (int i = 0; i < 8; ++i) *(float2*)&dst[2 * i] = src[i];
            dst[16] = n32[r];
        }
    }
    __syncthreads();

    // ---- phase D: exact fp32 top-2 over 512 codes; flag near-ties ----
    {
        const float* cbf = (const float*)sbuf;
        const int s  = tid & 31;        // 32 lanes/token-group, 16 codes each
        const int tD = (tid >> 5) * 4;  // 4 tokens per thread
        float e[4][CD];
        #pragma unroll
        for (int j = 0; j < 4; ++j)
            #pragma unroll
            for (int q4 = 0; q4 < 4; ++q4) {
                float4 v = *(const float4*)&embs[(tD + j) * CD + q4 * 4];
                e[j][q4 * 4 + 0] = v.x; e[j][q4 * 4 + 1] = v.y;
                e[j][q4 * 4 + 2] = v.z; e[j][q4 * 4 + 3] = v.w;
            }
        float d1[4], d2[4]; int i1[4], i2[4];
        #pragma unroll
        for (int j = 0; j < 4; ++j) { d1[j] = d2[j] = 3.4e38f; i1[j] = i2[j] = 0x7fffffff; }

        for (int cc = 0; cc < 16; ++cc) {
            const int ci = cc * 32 + s;
            const float* cr = &cbf[ci * 18];
            float c_[CD];
            #pragma unroll
            for (int i = 0; i < 8; ++i) {
                float2 p = *(const float2*)&cr[2 * i];
                c_[2 * i] = p.x; c_[2 * i + 1] = p.y;
            }
            float cn = cr[16];
            #pragma unroll
            for (int j = 0; j < 4; ++j) {
                float dA = 0.f, dB = 0.f;
                #pragma unroll
                for (int p = 0; p < 8; ++p) {
                    dA = fmaf(c_[2 * p],     e[j][2 * p],     dA);
                    dB = fmaf(c_[2 * p + 1], e[j][2 * p + 1], dB);
                }
                float d = fmaf(-2.f, dA + dB, cn);
                if (d < d1[j])      { d2[j] = d1[j]; i2[j] = i1[j]; d1[j] = d; i1[j] = ci; }
                else if (d < d2[j]) { d2[j] = d;  i2[j] = ci; }
            }
        }
        #pragma unroll
        for (int off = 16; off >= 1; off >>= 1) {
            #pragma unroll
            for (int j = 0; j < 4; ++j) {
                float od1 = __shfl_down(d1[j], off, 32);
                int   oi1 = __shfl_down(i1[j], off, 32);
                float od2 = __shfl_down(d2[j], off, 32);
                int   oi2 = __shfl_down(i2[j], off, 32);
                bool ob = (od1 < d1[j]) || (od1 == d1[j] && oi1 < i1[j]);
                float n1d, n2d; int n1i, n2i;
                if (ob) {
                    n1d = od1; n1i = oi1;
                    bool t2 = (d1[j] < od2) || (d1[j] == od2 && i1[j] < oi2);
                    n2d = t2 ? d1[j] : od2; n2i = t2 ? i1[j] : oi2;
                } else {
                    n1d = d1[j]; n1i = i1[j];
                    bool t2 = (od1 < d2[j]) || (od1 == d2[j] && oi1 < i2[j]);
                    n2d = t2 ? od1 : d2[j]; n2i = t2 ? oi1 : i2[j];
                }
                d1[j] = n1d; i1[j] = n1i; d2[j] = n2d; i2[j] = n2i;
            }
        }
        if (s == 0) {
            int nf = 0, ft[4];
            #pragma unroll
            for (int j = 0; j < 4; ++j) {
                int T = blk * OBS + tD + j;
                idxbuf[T] = i1[j];
                if (d2[j] - d1[j] < EPS) ft[nf++] = T;
            }
            if (nf) {
                int base = atomicAdd(fcnt, nf);
                for (int k = 0; k < nf; ++k) flist[base + k] = ft[k];
            }
        }
    }
}

// ---------------------------------------------------------------------------
// Kernel 2: fp64 exact re-solve for flagged tokens (from ORIGINAL fp32 data;
// independent of the encoder's split path). Overwrites idxbuf[T].
// ---------------------------------------------------------------------------
__global__ void __launch_bounds__(256) fixup_kernel(
    const float* __restrict__ obs,
    const float* __restrict__ W0, const float* __restrict__ B0,
    const float* __restrict__ W1, const float* __restrict__ B1,
    const float* __restrict__ W2, const float* __restrict__ B2,
    const float* __restrict__ cb, const double* __restrict__ n64,
    const int* __restrict__ fcnt, const int* __restrict__ flist,
    int* __restrict__ idxbuf)
{
    __shared__ double h0s[HD];
    __shared__ double h1s[HD];
    __shared__ double ep[16][17];
    __shared__ double es[CD];
    __shared__ double dmin[256];
    __shared__ int    imin[256];

    int n = *fcnt;
    if (n > BATCH * OBS) n = BATCH * OBS;
    const int j = threadIdx.x;

    for (int f = blockIdx.x; f < n; f += gridDim.x) {
        const int T = flist[f];
        const int b = T >> 5, t = T & 31;
        const double x = (double)obs[b * OBS + t];
        {
            double a = fma(x, (double)W0[j], (double)W0[(1 + t) * HD + j])
                     + (double)B0[j];
            h0s[j] = a > 0.0 ? a : 0.0;
        }
        __syncthreads();
        {
            double s = 0.0;
            for (int k = 0; k < HD; ++k)
                s = fma(h0s[k], (double)W1[k * HD + j], s);
            s += (double)B1[j];
            h1s[j] = s > 0.0 ? s : 0.0;
        }
        __syncthreads();
        {
            const int d = j & 15, part = j >> 4;
            double s = 0.0;
            for (int k = part * 16; k < part * 16 + 16; ++k)
                s = fma(h1s[k], (double)W2[k * CD + d], s);
            ep[part][d] = s;
        }
        __syncthreads();
        if (j < CD) {
            double s = 0.0;
            for (int p = 0; p < 16; ++p) s += ep[p][j];
            es[j] = s + (double)B2[j];
        }
        __syncthreads();
        {
            double best = 1e300; int bi = 0x7fffffff;
            for (int c = j; c < NC; c += 256) {
                double dot = 0.0;
                #pragma unroll
                for (int qq = 0; qq < CD; ++qq)
                    dot = fma(es[qq], (double)cb[c * CD + qq], dot);
                double D = n64[c] - 2.0 * dot;
                if (D < best || (D == best && c < bi)) { best = D; bi = c; }
            }
            dmin[j] = best; imin[j] = bi;
        }
        __syncthreads();
        if (j == 0) {
            double best = dmin[0]; int bi = imin[0];
            for (int k = 1; k < 256; ++k)
                if (dmin[k] < best || (dmin[k] == best && imin[k] < bi)) {
                    best = dmin[k]; bi = imin[k];
                }
            idxbuf[T] = bi;
        }
        __syncthreads();
    }
}

// ---------------------------------------------------------------------------
// Kernel 3: decoder MLP 512 -> 256 -> 256 -> 32, 16 batch rows per block.
// ---------------------------------------------------------------------------
__global__ void __launch_bounds__(256) decoder_kernel(
    const int* __restrict__ idx, const float* __restrict__ cbk,
    const float* __restrict__ W0, const float* __restrict__ B0,
    const float* __restrict__ W1, const float* __restrict__ B1,
    const float* __restrict__ W2, const float* __restrict__ B2,
    float* __restrict__ out)
{
    __shared__ float qb[16][512];
    __shared__ float hb[16][256];
    const int tid = threadIdx.x;
    const int row0 = blockIdx.x * 16;

    {
        const int base = row0 * OBS;
        #pragma unroll
        for (int m = 0; m < 2; ++m) {
            int g = tid * 2 + m;
            int ciq = idx[base + g];
            const float4* src = (const float4*)(cbk + ciq * CD);
            float4* dst = (float4*)&qb[g >> 5][(g & 31) * CD];
            dst[0] = src[0]; dst[1] = src[1]; dst[2] = src[2]; dst[3] = src[3];
        }
    }
    __syncthreads();

    const int jg = tid & 63, tg = tid >> 6;
    const int j0 = jg * 4, r0 = tg * 4;

    {
        float acA[4][4], acB[4][4];
        #pragma unroll
        for (int tt = 0; tt < 4; ++tt)
            #pragma unroll
            for (int u = 0; u < 4; ++u) { acA[tt][u] = 0.f; acB[tt][u] = 0.f; }
        for (int k = 0; k < 512; k += 4) {
            float hr[4][4];
            #pragma unroll
            for (int tt = 0; tt < 4; ++tt) {
                float4 hv = *(const float4*)&qb[r0 + tt][k];
                hr[tt][0] = hv.x; hr[tt][1] = hv.y; hr[tt][2] = hv.z; hr[tt][3] = hv.w;
            }
            #pragma unroll
            for (int p = 0; p < 4; ++p) {
                float4 w = *(const float4*)(W0 + (k + p) * 256 + j0);
                if (p < 2) {
                    #pragma unroll
                    for (int tt = 0; tt < 4; ++tt) {
                        acA[tt][0] = fmaf(hr[tt][p], w.x, acA[tt][0]);
                        acA[tt][1] = fmaf(hr[tt][p], w.y, acA[tt][1]);
                        acA[tt][2] = fmaf(hr[tt][p], w.z, acA[tt][2]);
                        acA[tt][3] = fmaf(hr[tt][p], w.w, acA[tt][3]);
                    }
                } else {
                    #pragma unroll
                    for (int tt = 0; tt < 4; ++tt) {
                        acB[tt][0] = fmaf(hr[tt][p], w.x, acB[tt][0]);
                        acB[tt][1] = fmaf(hr[tt][p], w.y, acB[tt][1]);
                        acB[tt][2] = fmaf(hr[tt][p], w.z, acB[tt][2]);
                        acB[tt][3] = fmaf(hr[tt][p], w.w, acB[tt][3]);
                    }
                }
            }
        }
        #pragma unroll
        for (int tt = 0; tt < 4; ++tt)
            #pragma unroll
            for (int u = 0; u < 4; ++u)
                hb[r0 + tt][j0 + u] = fmaxf((acA[tt][u] + acB[tt][u]) + B0[j0 + u], 0.f);
    }
    __syncthreads();

    float* h2 = &qb[0][0];
    {
        float acA[4][4], acB[4][4];
        #pragma unroll
        for (int tt = 0; tt < 4; ++tt)
            #pragma unroll
            for (int u = 0; u < 4; ++u) { acA[tt][u] = 0.f; acB[tt][u] = 0.f; }
        for (int k = 0; k < 256; k += 4) {
            float hr[4][4];
            #pragma unroll
            for (int tt = 0; tt < 4; ++tt) {
                float4 hv = *(const float4*)&hb[r0 + tt][k];
                hr[tt][0] = hv.x; hr[tt][1] = hv.y; hr[tt][2] = hv.z; hr[tt][3] = hv.w;
            }
            #pragma unroll
            for (int p = 0; p < 4; ++p) {
                float4 w = *(const float4*)(W1 + (k + p) * 256 + j0);
                if (p < 2) {
                    #pragma unroll
                    for (int tt = 0; tt < 4; ++tt) {
                        acA[tt][0] = fmaf(hr[tt][p], w.x, acA[tt][0]);
                        acA[tt][1] = fmaf(hr[tt][p], w.y, acA[tt][1]);
                        acA[tt][2] = fmaf(hr[tt][p], w.z, acA[tt][2]);
                        acA[tt][3] = fmaf(hr[tt][p], w.w, acA[tt][3]);
                    }
                } else {
                    #pragma unroll
                    for (int tt = 0; tt < 4; ++tt) {
                        acB[tt][0] = fmaf(hr[tt][p], w.x, acB[tt][0]);
                        acB[tt][1] = fmaf(hr[tt][p], w.y, acB[tt][1]);
                        acB[tt][2] = fmaf(hr[tt][p], w.z, acB[tt][2]);
                        acB[tt][3] = fmaf(hr[tt][p], w.w, acB[tt][3]);
                    }
                }
            }
        }
        __syncthreads();
        #pragma unroll
        for (int tt = 0; tt < 4; ++tt)
            #pragma unroll
            for (int u = 0; u < 4; ++u)
                h2[(r0 + tt) * 256 + j0 + u] =
                    fmaxf((acA[tt][u] + acB[tt][u]) + B1[j0 + u], 0.f);
    }
    __syncthreads();

    {
        const int c  = tid & 31;
        const int rg = tid >> 5;
        for (int rr = rg; rr < 16; rr += 8) {
            float a0 = 0.f, a1 = 0.f, a2 = 0.f, a3 = 0.f;
            #pragma unroll 4
            for (int k = 0; k < 256; k += 4) {
                float4 hv = *(const float4*)&h2[rr * 256 + k];
                a0 = fmaf(hv.x, W2[(k + 0) * 32 + c], a0);
                a1 = fmaf(hv.y, W2[(k + 1) * 32 + c], a1);
                a2 = fmaf(hv.z, W2[(k + 2) * 32 + c], a2);
                a3 = fmaf(hv.w, W2[(k + 3) * 32 + c], a3);
            }
            out[(row0 + rr) * 32 + c] = ((a0 + a1) + (a2 + a3)) + B2[c];
        }
    }
}

// ---------------------------------------------------------------------------
extern "C" void kernel_launch(void* const* d_in, const int* in_sizes, int n_in,
                              void* d_out, int out_size, void* d_ws, size_t ws_size,
                              hipStream_t stream) {
    (void)in_sizes; (void)n_in; (void)out_size; (void)ws_size;
    const float* obs = (const float*)d_in[0];
    const float* eW0 = (const float*)d_in[1];
    const float* eb0 = (const float*)d_in[2];
    const float* eW1 = (const float*)d_in[3];
    const float* eb1 = (const float*)d_in[4];
    const float* eW2 = (const float*)d_in[5];
    const float* eb2 = (const float*)d_in[6];
    const float* dW0 = (const float*)d_in[7];
    const float* db0 = (const float*)d_in[8];
    const float* dW1 = (const float*)d_in[9];
    const float* db1 = (const float*)d_in[10];
    const float* dW2 = (const float*)d_in[11];
    const float* db2 = (const float*)d_in[12];
    const float* cb  = (const float*)d_in[13];

    char*   ws    = (char*)d_ws;
    float*  n32   = (float*)ws;                          // 2 KB
    double* n64   = (double*)(ws + 4096);                // 4 KB
    int*    fcnt  = (int*)(ws + 8192);                   // 4 B
    int*    flist = (int*)(ws + 8448);                   // 1 MB
    int*    idxb  = (int*)(ws + 8448 + 1048576);         // 1 MB
    u16*    wsW1  = (u16*)(ws + 4194304);                // 256 KB (8 chunks)
    u16*    wsW2  = (u16*)(ws + 4194304 + 262144);       // 16.5 KB

    prep_kernel<<<258, 256, 0, stream>>>(cb, eW1, eW2, n32, n64, fcnt,
                                         wsW1, wsW2);
    encoder_kernel<<<BATCH, 256, 0, stream>>>(obs, eW0, eb0, eb1, eb2,
                                              wsW1, wsW2, cb, n32,
                                              idxb, fcnt, flist);
    fixup_kernel<<<256, 256, 0, stream>>>(obs, eW0, eb0, eW1, eb1, eW2, eb2,
                                          cb, n64, fcnt, flist, idxb);
    decoder_kernel<<<BATCH / 16, 256, 0, stream>>>(idxb, cb, dW0, db0, dW1, db1,
                                                   dW2, db2, (float*)d_out);
}